// Round 4
// baseline (396.229 us; speedup 1.0000x reference)
//
#include <hip/hip_runtime.h>

#define NB 8
#define NC 512
#define NL 2048
#define NH 8
#define ND 64
#define NHID 512

typedef float f32x4 __attribute__((ext_vector_type(4)));
typedef short bf16x8 __attribute__((ext_vector_type(8)));
typedef unsigned uint32x2 __attribute__((ext_vector_type(2)));

__device__ __forceinline__ unsigned short f2bf(float x) {
    unsigned u = __float_as_uint(x);
    u += 0x7fffu + ((u >> 16) & 1u);
    return (unsigned short)(u >> 16);
}

__device__ __forceinline__ unsigned pack_bf16_ru(float lo, float hi) {
    unsigned a = __float_as_uint(lo) + 0x8000u;
    unsigned b = __float_as_uint(hi) + 0x8000u;
#if __has_builtin(__builtin_amdgcn_perm)
    return __builtin_amdgcn_perm(b, a, 0x07060302u);
#else
    return (a >> 16) | (b & 0xffff0000u);
#endif
}

__device__ __forceinline__ float fexp2(float x) {
#if __has_builtin(__builtin_amdgcn_exp2f)
    return __builtin_amdgcn_exp2f(x);
#else
    return exp2f(x);
#endif
}

// C/D-layout -> B-frag relayout (register-only transpose across quads)
__device__ __forceinline__ void pfr_quad_swap(unsigned &a, unsigned &b) {
#if __has_builtin(__builtin_amdgcn_permlane32_swap) && __has_builtin(__builtin_amdgcn_permlane16_swap)
    uint32x2 r0 = __builtin_amdgcn_permlane32_swap(a, b, false, false);
    uint32x2 r1 = __builtin_amdgcn_permlane16_swap(r0[0], r0[1], false, false);
    a = r1[0];
    b = r1[1];
#else
    const int lane = (int)(threadIdx.x & 63);
    const int li = lane & 15, quad = lane >> 4;
    const int s0 = (li + ((quad & 1) << 5)) << 2;
    const int s1 = (li + 16 + ((quad & 1) << 5)) << 2;
    int ra = __builtin_amdgcn_ds_bpermute(s0, (int)a);
    int rb = __builtin_amdgcn_ds_bpermute(s0, (int)b);
    int ta = __builtin_amdgcn_ds_bpermute(s1, (int)a);
    int tb = __builtin_amdgcn_ds_bpermute(s1, (int)b);
    const bool lo = quad < 2;
    a = (unsigned)(lo ? ra : rb);
    b = (unsigned)(lo ? ta : tb);
#endif
}

// ---------------------------------------------------------------------------
// Kernel 1: QKV projection with register-prefetch software pipeline.
// ---------------------------------------------------------------------------
__global__ __launch_bounds__(256) void qkv_proj_kernel(
    const float* __restrict__ x, const float* __restrict__ w,
    unsigned short* __restrict__ qb, unsigned short* __restrict__ kb,
    unsigned short* __restrict__ vb)
{
    __shared__ __align__(16) unsigned short XT[128 * 40];
    __shared__ __align__(16) unsigned short WT[128 * 40];
    const int tid = threadIdx.x;
    const int wave = tid >> 6, lane = tid & 63;
    const int quad = lane >> 4, li = lane & 15;
    const int o0 = blockIdx.x * 128, l0 = blockIdx.y * 128, b = blockIdx.z;

    const f32x4 fzero = {0.f, 0.f, 0.f, 0.f};
    f32x4 acc[2][8];
    #pragma unroll
    for (int mt = 0; mt < 2; mt++)
        #pragma unroll
        for (int nt = 0; nt < 8; nt++) acc[mt][nt] = fzero;

    const int xl = tid & 127, xg = tid >> 7;
    const int wcg = tid & 7, woo = tid >> 3;

    float xv[2][8];
    float4 wv[4];
    // prologue: prefetch c0 = 0
    #pragma unroll
    for (int i = 0; i < 2; i++) {
        const int cch = xg + 2 * i;
        const float* xs = x + ((size_t)(b * NC + cch * 8)) * NL + l0 + xl;
        #pragma unroll
        for (int k = 0; k < 8; k++) xv[i][k] = xs[(size_t)k * NL];
    }
    #pragma unroll
    for (int rep = 0; rep < 4; rep++)
        wv[rep] = *(const float4*)&w[(size_t)(o0 + woo + rep * 32) * NC + wcg * 4];

    for (int c0 = 0; c0 < NC; c0 += 32) {
        // store staged regs -> LDS (convert to bf16)
        #pragma unroll
        for (int i = 0; i < 2; i++) {
            const int cch = xg + 2 * i;
            unsigned p[4];
            #pragma unroll
            for (int k2 = 0; k2 < 4; k2++)
                p[k2] = (unsigned)f2bf(xv[i][2 * k2]) |
                        ((unsigned)f2bf(xv[i][2 * k2 + 1]) << 16);
            uint4 val; val.x = p[0]; val.y = p[1]; val.z = p[2]; val.w = p[3];
            *(uint4*)&XT[xl * 40 + cch * 8] = val;
        }
        #pragma unroll
        for (int rep = 0; rep < 4; rep++) {
            uint2 val;
            val.x = (unsigned)f2bf(wv[rep].x) | ((unsigned)f2bf(wv[rep].y) << 16);
            val.y = (unsigned)f2bf(wv[rep].z) | ((unsigned)f2bf(wv[rep].w) << 16);
            *(uint2*)&WT[(woo + rep * 32) * 40 + wcg * 4] = val;
        }
        __syncthreads();
        // prefetch next K-slab while computing on this one
        if (c0 + 32 < NC) {
            const int c1 = c0 + 32;
            #pragma unroll
            for (int i = 0; i < 2; i++) {
                const int cch = xg + 2 * i;
                const float* xs = x + ((size_t)(b * NC + c1 + cch * 8)) * NL + l0 + xl;
                #pragma unroll
                for (int k = 0; k < 8; k++) xv[i][k] = xs[(size_t)k * NL];
            }
            #pragma unroll
            for (int rep = 0; rep < 4; rep++)
                wv[rep] = *(const float4*)&w[(size_t)(o0 + woo + rep * 32) * NC + c1 + wcg * 4];
        }
        bf16x8 afr0 = *(const bf16x8*)&XT[(wave * 32 + li) * 40 + quad * 8];
        bf16x8 afr1 = *(const bf16x8*)&XT[(wave * 32 + 16 + li) * 40 + quad * 8];
        #pragma unroll
        for (int nt = 0; nt < 8; nt++) {
            bf16x8 bfr = *(const bf16x8*)&WT[(nt * 16 + li) * 40 + quad * 8];
            acc[0][nt] = __builtin_amdgcn_mfma_f32_16x16x32_bf16(afr0, bfr, acc[0][nt], 0, 0, 0);
            acc[1][nt] = __builtin_amdgcn_mfma_f32_16x16x32_bf16(afr1, bfr, acc[1][nt], 0, 0, 0);
        }
        __syncthreads();
    }

    const int lr0 = l0 + wave * 32;
    if (o0 < 1024) {
        unsigned short* dst = (o0 < 512) ? qb : kb;
        const float scale = (o0 < 512) ? (0.125f * 1.44269504088896f) : 1.0f;
        #pragma unroll
        for (int mt = 0; mt < 2; mt++)
            #pragma unroll
            for (int nt = 0; nt < 8; nt++) {
                int oc = (o0 & 511) + nt * 16 + li;
                int hh = oc >> 6, d = oc & 63;
                size_t base =
                    ((size_t)((b * NH + hh) * NL) + lr0 + mt * 16 + quad * 4) * ND + d;
                #pragma unroll
                for (int r = 0; r < 4; r++)
                    dst[base + (size_t)r * ND] = f2bf(acc[mt][nt][r] * scale);
            }
    } else {
        #pragma unroll
        for (int mt = 0; mt < 2; mt++)
            #pragma unroll
            for (int nt = 0; nt < 8; nt++) {
                int oc = (o0 - 1024) + nt * 16 + li;
                int hh = oc >> 6, d = oc & 63;
                size_t base = ((size_t)((b * NH + hh) * ND) + d) * NL +
                              lr0 + mt * 16 + quad * 4;
                uint2 pv;
                pv.x = (unsigned)f2bf(acc[mt][nt][0]) | ((unsigned)f2bf(acc[mt][nt][1]) << 16);
                pv.y = (unsigned)f2bf(acc[mt][nt][2]) | ((unsigned)f2bf(acc[mt][nt][3]) << 16);
                *(uint2*)&vb[base] = pv;
            }
    }
}

// ---------------------------------------------------------------------------
// Kernel 2: flash attention, transposed scores + fixed-base softmax +
// register-prefetch software pipeline for the K/V staging.
// ---------------------------------------------------------------------------
__global__ __launch_bounds__(256) void attn_kernel(
    const unsigned short* __restrict__ qb, const unsigned short* __restrict__ kb,
    const unsigned short* __restrict__ vb, unsigned short* __restrict__ at)
{
    __shared__ __align__(16) unsigned short Kt[128 * 72];  // [j][d], pad 64->72
    __shared__ __align__(16) unsigned short Vt[64 * 136];  // [d][j], pad 128->136
    const int tid = threadIdx.x;
    const int wave = tid >> 6, lane = tid & 63;
    const int quad = lane >> 4, li = lane & 15;
    const int qt = blockIdx.x, h = blockIdx.y, b = blockIdx.z;
    const int bh = b * NH + h;
    const unsigned short* Qb = qb + (size_t)bh * NL * ND;
    const unsigned short* Kb = kb + (size_t)bh * NL * ND;
    const unsigned short* Vb = vb + (size_t)bh * ND * NL;

    bf16x8 qfr[2][2];
    #pragma unroll
    for (int mt = 0; mt < 2; mt++)
        #pragma unroll
        for (int kc = 0; kc < 2; kc++)
            qfr[mt][kc] = *(const bf16x8*)&Qb[(size_t)(qt * 128 + wave * 32 + mt * 16 + li) * ND +
                                             kc * 32 + quad * 8];

    const f32x4 fzero = {0.f, 0.f, 0.f, 0.f};
    float lsum[2] = {0.f, 0.f};
    f32x4 oacc[2][4];
    #pragma unroll
    for (int mt = 0; mt < 2; mt++)
        #pragma unroll
        for (int dt = 0; dt < 4; dt++) oacc[mt][dt] = fzero;

    const int kch = tid & 7, kjj = tid >> 3;
    const int vch = tid & 15, vdd = tid >> 4;

    uint4 kreg[4], vreg[4];
    // prologue: prefetch tile 0
    #pragma unroll
    for (int rep = 0; rep < 4; rep++) {
        kreg[rep] = *(const uint4*)&Kb[(size_t)(kjj + rep * 32) * ND + kch * 8];
        vreg[rep] = *(const uint4*)&Vb[(size_t)(vdd + rep * 16) * NL + vch * 8];
    }

    for (int kt = 0; kt < 16; kt++) {
        // store staged tile -> LDS
        #pragma unroll
        for (int rep = 0; rep < 4; rep++) {
            *(uint4*)&Kt[(kjj + rep * 32) * 72 + kch * 8] = kreg[rep];
            *(uint4*)&Vt[(vdd + rep * 16) * 136 + vch * 8] = vreg[rep];
        }
        __syncthreads();
        // prefetch next tile; stays in flight across the whole compute phase
        if (kt < 15) {
            const int j0n = (kt + 1) * 128;
            #pragma unroll
            for (int rep = 0; rep < 4; rep++) {
                kreg[rep] = *(const uint4*)&Kb[(size_t)(j0n + kjj + rep * 32) * ND + kch * 8];
                vreg[rep] = *(const uint4*)&Vb[(size_t)(vdd + rep * 16) * NL + j0n + vch * 8];
            }
        }

        // S^T = K Q^T
        f32x4 st[2][8];
        #pragma unroll
        for (int mt = 0; mt < 2; mt++)
            #pragma unroll
            for (int jt = 0; jt < 8; jt++) st[mt][jt] = fzero;
        #pragma unroll
        for (int kc = 0; kc < 2; kc++)
            #pragma unroll
            for (int jt = 0; jt < 8; jt++) {
                bf16x8 kfr = *(const bf16x8*)&Kt[(jt * 16 + li) * 72 + kc * 32 + quad * 8];
                st[0][jt] = __builtin_amdgcn_mfma_f32_16x16x32_bf16(kfr, qfr[0][kc], st[0][jt], 0, 0, 0);
                st[1][jt] = __builtin_amdgcn_mfma_f32_16x16x32_bf16(kfr, qfr[1][kc], st[1][jt], 0, 0, 0);
            }

        // P = exp2(S), per-lane row-sum, bf16 pack
        unsigned pk[2][8][2];
        #pragma unroll
        for (int mt = 0; mt < 2; mt++) {
            float ps = 0.f;
            #pragma unroll
            for (int jt = 0; jt < 8; jt++) {
                float p0 = fexp2(st[mt][jt][0]);
                float p1 = fexp2(st[mt][jt][1]);
                float p2 = fexp2(st[mt][jt][2]);
                float p3 = fexp2(st[mt][jt][3]);
                ps += (p0 + p1) + (p2 + p3);
                pk[mt][jt][0] = pack_bf16_ru(p0, p1);
                pk[mt][jt][1] = pack_bf16_ru(p2, p3);
            }
            lsum[mt] += ps;
        }

        // register relayout C/D -> B-frags
        #pragma unroll
        for (int mt = 0; mt < 2; mt++)
            #pragma unroll
            for (int kc = 0; kc < 4; kc++)
                #pragma unroll
                for (int p = 0; p < 2; p++)
                    pfr_quad_swap(pk[mt][2 * kc][p], pk[mt][2 * kc + 1][p]);

        // O^T += V^T P^T
        #pragma unroll
        for (int kc = 0; kc < 4; kc++) {
            union { unsigned u[4]; bf16x8 v; } pf0, pf1;
            pf0.u[0] = pk[0][2 * kc][0]; pf0.u[1] = pk[0][2 * kc][1];
            pf0.u[2] = pk[0][2 * kc + 1][0]; pf0.u[3] = pk[0][2 * kc + 1][1];
            pf1.u[0] = pk[1][2 * kc][0]; pf1.u[1] = pk[1][2 * kc][1];
            pf1.u[2] = pk[1][2 * kc + 1][0]; pf1.u[3] = pk[1][2 * kc + 1][1];
            #pragma unroll
            for (int dt = 0; dt < 4; dt++) {
                bf16x8 vfr = *(const bf16x8*)&Vt[(dt * 16 + li) * 136 + kc * 32 + quad * 8];
                oacc[0][dt] = __builtin_amdgcn_mfma_f32_16x16x32_bf16(vfr, pf0.v, oacc[0][dt], 0, 0, 0);
                oacc[1][dt] = __builtin_amdgcn_mfma_f32_16x16x32_bf16(vfr, pf1.v, oacc[1][dt], 0, 0, 0);
            }
        }
        __syncthreads();
    }

    #pragma unroll
    for (int mt = 0; mt < 2; mt++) {
        float s = lsum[mt];
        s += __shfl_xor(s, 16, 64);
        s += __shfl_xor(s, 32, 64);
        lsum[mt] = s;
    }

    #pragma unroll
    for (int mt = 0; mt < 2; mt++) {
        const float rl = 1.0f / lsum[mt];
        const int l = qt * 128 + wave * 32 + mt * 16 + li;
        #pragma unroll
        for (int dt = 0; dt < 4; dt++) {
            uint2 ov;
            ov.x = (unsigned)f2bf(oacc[mt][dt][0] * rl) |
                   ((unsigned)f2bf(oacc[mt][dt][1] * rl) << 16);
            ov.y = (unsigned)f2bf(oacc[mt][dt][2] * rl) |
                   ((unsigned)f2bf(oacc[mt][dt][3] * rl) << 16);
            *(uint2*)&at[((size_t)(b * NL + l)) * NHID + h * ND + dt * 16 + quad * 4] = ov;
        }
    }
}

// ---------------------------------------------------------------------------
// Kernel 3: output projection with register-prefetch software pipeline.
// ---------------------------------------------------------------------------
__global__ __launch_bounds__(256) void out_proj_kernel(
    const unsigned short* __restrict__ at, const float* __restrict__ w,
    const float* __restrict__ bias, float* __restrict__ out)
{
    __shared__ __align__(16) unsigned short Wl[128 * 40];
    __shared__ __align__(16) unsigned short Al[128 * 40];
    const int tid = threadIdx.x;
    const int wave = tid >> 6, lane = tid & 63;
    const int quad = lane >> 4, li = lane & 15;
    const int o0 = blockIdx.x * 128, l0 = blockIdx.y * 128, b = blockIdx.z;

    const f32x4 fzero = {0.f, 0.f, 0.f, 0.f};
    f32x4 acc[2][8];
    #pragma unroll
    for (int mt = 0; mt < 2; mt++)
        #pragma unroll
        for (int nt = 0; nt < 8; nt++) acc[mt][nt] = fzero;

    const int wcg = tid & 7, woo = tid >> 3;
    const int ach = tid & 3, al0 = tid >> 2;

    float4 wv[4];
    uint4 av[2];
    #pragma unroll
    for (int rep = 0; rep < 4; rep++)
        wv[rep] = *(const float4*)&w[(size_t)(o0 + woo + rep * 32) * NHID + wcg * 4];
    #pragma unroll
    for (int rep = 0; rep < 2; rep++)
        av[rep] = *(const uint4*)&at[(size_t)(b * NL + l0 + al0 + rep * 64) * NHID + ach * 8];

    for (int c0 = 0; c0 < NHID; c0 += 32) {
        #pragma unroll
        for (int rep = 0; rep < 4; rep++) {
            uint2 val;
            val.x = (unsigned)f2bf(wv[rep].x) | ((unsigned)f2bf(wv[rep].y) << 16);
            val.y = (unsigned)f2bf(wv[rep].z) | ((unsigned)f2bf(wv[rep].w) << 16);
            *(uint2*)&Wl[(woo + rep * 32) * 40 + wcg * 4] = val;
        }
        #pragma unroll
        for (int rep = 0; rep < 2; rep++)
            *(uint4*)&Al[(al0 + rep * 64) * 40 + ach * 8] = av[rep];
        __syncthreads();
        if (c0 + 32 < NHID) {
            const int c1 = c0 + 32;
            #pragma unroll
            for (int rep = 0; rep < 4; rep++)
                wv[rep] = *(const float4*)&w[(size_t)(o0 + woo + rep * 32) * NHID + c1 + wcg * 4];
            #pragma unroll
            for (int rep = 0; rep < 2; rep++)
                av[rep] = *(const uint4*)&at[(size_t)(b * NL + l0 + al0 + rep * 64) * NHID + c1 + ach * 8];
        }
        bf16x8 afr0 = *(const bf16x8*)&Wl[(wave * 32 + li) * 40 + quad * 8];
        bf16x8 afr1 = *(const bf16x8*)&Wl[(wave * 32 + 16 + li) * 40 + quad * 8];
        #pragma unroll
        for (int nt = 0; nt < 8; nt++) {
            bf16x8 bfr = *(const bf16x8*)&Al[(nt * 16 + li) * 40 + quad * 8];
            acc[0][nt] = __builtin_amdgcn_mfma_f32_16x16x32_bf16(afr0, bfr, acc[0][nt], 0, 0, 0);
            acc[1][nt] = __builtin_amdgcn_mfma_f32_16x16x32_bf16(afr1, bfr, acc[1][nt], 0, 0, 0);
        }
        __syncthreads();
    }

    #pragma unroll
    for (int mt = 0; mt < 2; mt++) {
        int or0 = o0 + wave * 32 + mt * 16 + quad * 4;
        #pragma unroll
        for (int nt = 0; nt < 8; nt++) {
            int l = l0 + nt * 16 + li;
            #pragma unroll
            for (int r = 0; r < 4; r++)
                out[((size_t)(b * NC + or0 + r)) * NL + l] = acc[mt][nt][r] + bias[or0 + r];
        }
    }
}

extern "C" void kernel_launch(void* const* d_in, const int* in_sizes, int n_in,
                              void* d_out, int out_size, void* d_ws, size_t ws_size,
                              hipStream_t stream) {
    const float* x = (const float*)d_in[0];
    const float* w_qkv = (const float*)d_in[1];
    const float* w_out = (const float*)d_in[2];
    const float* b_out = (const float*)d_in[3];
    float* out = (float*)d_out;

    unsigned short* ws = (unsigned short*)d_ws;
    const size_t SZ = (size_t)NB * NH * NL * ND;
    unsigned short* qb = ws;
    unsigned short* kb = qb + SZ;
    unsigned short* vb = kb + SZ;
    unsigned short* at = vb + SZ;

    qkv_proj_kernel<<<dim3(12, 16, 8), dim3(256), 0, stream>>>(x, w_qkv, qb, kb, vb);
    attn_kernel<<<dim3(16, 8, 8), dim3(256), 0, stream>>>(qb, kb, vb, at);
    out_proj_kernel<<<dim3(4, 16, 8), dim3(256), 0, stream>>>(at, w_out, b_out, out);
}

// Round 5
// 345.754 us; speedup vs baseline: 1.1460x; 1.1460x over previous
//
#include <hip/hip_runtime.h>

#define NB 8
#define NC 512
#define NL 2048
#define NH 8
#define ND 64
#define NHID 512

typedef float f32x4 __attribute__((ext_vector_type(4)));
typedef short bf16x8 __attribute__((ext_vector_type(8)));
typedef unsigned uint32x2 __attribute__((ext_vector_type(2)));

__device__ __forceinline__ unsigned short f2bf(float x) {
    unsigned u = __float_as_uint(x);
    u += 0x7fffu + ((u >> 16) & 1u);
    return (unsigned short)(u >> 16);
}

__device__ __forceinline__ unsigned pack_bf16_ru(float lo, float hi) {
    unsigned a = __float_as_uint(lo) + 0x8000u;
    unsigned b = __float_as_uint(hi) + 0x8000u;
#if __has_builtin(__builtin_amdgcn_perm)
    return __builtin_amdgcn_perm(b, a, 0x07060302u);
#else
    return (a >> 16) | (b & 0xffff0000u);
#endif
}

__device__ __forceinline__ float fexp2(float x) {
#if __has_builtin(__builtin_amdgcn_exp2f)
    return __builtin_amdgcn_exp2f(x);
#else
    return exp2f(x);
#endif
}

// C/D-layout -> B-frag relayout (register-only transpose across quads)
__device__ __forceinline__ void pfr_quad_swap(unsigned &a, unsigned &b) {
#if __has_builtin(__builtin_amdgcn_permlane32_swap) && __has_builtin(__builtin_amdgcn_permlane16_swap)
    uint32x2 r0 = __builtin_amdgcn_permlane32_swap(a, b, false, false);
    uint32x2 r1 = __builtin_amdgcn_permlane16_swap(r0[0], r0[1], false, false);
    a = r1[0];
    b = r1[1];
#else
    const int lane = (int)(threadIdx.x & 63);
    const int li = lane & 15, quad = lane >> 4;
    const int s0 = (li + ((quad & 1) << 5)) << 2;
    const int s1 = (li + 16 + ((quad & 1) << 5)) << 2;
    int ra = __builtin_amdgcn_ds_bpermute(s0, (int)a);
    int rb = __builtin_amdgcn_ds_bpermute(s0, (int)b);
    int ta = __builtin_amdgcn_ds_bpermute(s1, (int)a);
    int tb = __builtin_amdgcn_ds_bpermute(s1, (int)b);
    const bool lo = quad < 2;
    a = (unsigned)(lo ? ra : rb);
    b = (unsigned)(lo ? ta : tb);
#endif
}

// ---------------------------------------------------------------------------
// Kernel 1: QKV projection with register-prefetch software pipeline.
// ---------------------------------------------------------------------------
__global__ __launch_bounds__(256) void qkv_proj_kernel(
    const float* __restrict__ x, const float* __restrict__ w,
    unsigned short* __restrict__ qb, unsigned short* __restrict__ kb,
    unsigned short* __restrict__ vb)
{
    __shared__ __align__(16) unsigned short XT[128 * 40];
    __shared__ __align__(16) unsigned short WT[128 * 40];
    const int tid = threadIdx.x;
    const int wave = tid >> 6, lane = tid & 63;
    const int quad = lane >> 4, li = lane & 15;
    const int o0 = blockIdx.x * 128, l0 = blockIdx.y * 128, b = blockIdx.z;

    const f32x4 fzero = {0.f, 0.f, 0.f, 0.f};
    f32x4 acc[2][8];
    #pragma unroll
    for (int mt = 0; mt < 2; mt++)
        #pragma unroll
        for (int nt = 0; nt < 8; nt++) acc[mt][nt] = fzero;

    const int xl = tid & 127, xg = tid >> 7;
    const int wcg = tid & 7, woo = tid >> 3;

    float xv[2][8];
    float4 wv[4];
    #pragma unroll
    for (int i = 0; i < 2; i++) {
        const int cch = xg + 2 * i;
        const float* xs = x + ((size_t)(b * NC + cch * 8)) * NL + l0 + xl;
        #pragma unroll
        for (int k = 0; k < 8; k++) xv[i][k] = xs[(size_t)k * NL];
    }
    #pragma unroll
    for (int rep = 0; rep < 4; rep++)
        wv[rep] = *(const float4*)&w[(size_t)(o0 + woo + rep * 32) * NC + wcg * 4];

    for (int c0 = 0; c0 < NC; c0 += 32) {
        #pragma unroll
        for (int i = 0; i < 2; i++) {
            const int cch = xg + 2 * i;
            unsigned p[4];
            #pragma unroll
            for (int k2 = 0; k2 < 4; k2++)
                p[k2] = (unsigned)f2bf(xv[i][2 * k2]) |
                        ((unsigned)f2bf(xv[i][2 * k2 + 1]) << 16);
            uint4 val; val.x = p[0]; val.y = p[1]; val.z = p[2]; val.w = p[3];
            *(uint4*)&XT[xl * 40 + cch * 8] = val;
        }
        #pragma unroll
        for (int rep = 0; rep < 4; rep++) {
            uint2 val;
            val.x = (unsigned)f2bf(wv[rep].x) | ((unsigned)f2bf(wv[rep].y) << 16);
            val.y = (unsigned)f2bf(wv[rep].z) | ((unsigned)f2bf(wv[rep].w) << 16);
            *(uint2*)&WT[(woo + rep * 32) * 40 + wcg * 4] = val;
        }
        __syncthreads();
        if (c0 + 32 < NC) {
            const int c1 = c0 + 32;
            #pragma unroll
            for (int i = 0; i < 2; i++) {
                const int cch = xg + 2 * i;
                const float* xs = x + ((size_t)(b * NC + c1 + cch * 8)) * NL + l0 + xl;
                #pragma unroll
                for (int k = 0; k < 8; k++) xv[i][k] = xs[(size_t)k * NL];
            }
            #pragma unroll
            for (int rep = 0; rep < 4; rep++)
                wv[rep] = *(const float4*)&w[(size_t)(o0 + woo + rep * 32) * NC + c1 + wcg * 4];
        }
        bf16x8 afr0 = *(const bf16x8*)&XT[(wave * 32 + li) * 40 + quad * 8];
        bf16x8 afr1 = *(const bf16x8*)&XT[(wave * 32 + 16 + li) * 40 + quad * 8];
        #pragma unroll
        for (int nt = 0; nt < 8; nt++) {
            bf16x8 bfr = *(const bf16x8*)&WT[(nt * 16 + li) * 40 + quad * 8];
            acc[0][nt] = __builtin_amdgcn_mfma_f32_16x16x32_bf16(afr0, bfr, acc[0][nt], 0, 0, 0);
            acc[1][nt] = __builtin_amdgcn_mfma_f32_16x16x32_bf16(afr1, bfr, acc[1][nt], 0, 0, 0);
        }
        __syncthreads();
    }

    const int lr0 = l0 + wave * 32;
    if (o0 < 1024) {
        unsigned short* dst = (o0 < 512) ? qb : kb;
        const float scale = (o0 < 512) ? (0.125f * 1.44269504088896f) : 1.0f;
        #pragma unroll
        for (int mt = 0; mt < 2; mt++)
            #pragma unroll
            for (int nt = 0; nt < 8; nt++) {
                int oc = (o0 & 511) + nt * 16 + li;
                int hh = oc >> 6, d = oc & 63;
                size_t base =
                    ((size_t)((b * NH + hh) * NL) + lr0 + mt * 16 + quad * 4) * ND + d;
                #pragma unroll
                for (int r = 0; r < 4; r++)
                    dst[base + (size_t)r * ND] = f2bf(acc[mt][nt][r] * scale);
            }
    } else {
        #pragma unroll
        for (int mt = 0; mt < 2; mt++)
            #pragma unroll
            for (int nt = 0; nt < 8; nt++) {
                int oc = (o0 - 1024) + nt * 16 + li;
                int hh = oc >> 6, d = oc & 63;
                size_t base = ((size_t)((b * NH + hh) * ND) + d) * NL +
                              lr0 + mt * 16 + quad * 4;
                uint2 pv;
                pv.x = (unsigned)f2bf(acc[mt][nt][0]) | ((unsigned)f2bf(acc[mt][nt][1]) << 16);
                pv.y = (unsigned)f2bf(acc[mt][nt][2]) | ((unsigned)f2bf(acc[mt][nt][3]) << 16);
                *(uint2*)&vb[base] = pv;
            }
    }
}

// ---------------------------------------------------------------------------
// Kernel 2: flash attention.  Register-prefetch pipeline, staggered issue
// (K after barrier, V after exp phase) + __launch_bounds__(256,3) so the
// prefetch registers are allocated instead of spilled (R4 lesson: at the
// default budget the compiler kept 96 VGPRs and spilled ~128B/thread/iter
// to scratch -> 495MB writes).  Peak pressure ~142 VGPR <= 168 cap.
// ---------------------------------------------------------------------------
__global__ __launch_bounds__(256, 3) void attn_kernel(
    const unsigned short* __restrict__ qb, const unsigned short* __restrict__ kb,
    const unsigned short* __restrict__ vb, unsigned short* __restrict__ at)
{
    __shared__ __align__(16) unsigned short Kt[128 * 72];  // [j][d], pad 64->72
    __shared__ __align__(16) unsigned short Vt[64 * 136];  // [d][j], pad 128->136
    const int tid = threadIdx.x;
    const int wave = tid >> 6, lane = tid & 63;
    const int quad = lane >> 4, li = lane & 15;
    const int qt = blockIdx.x, h = blockIdx.y, b = blockIdx.z;
    const int bh = b * NH + h;
    const unsigned short* Qb = qb + (size_t)bh * NL * ND;
    const unsigned short* Kb = kb + (size_t)bh * NL * ND;
    const unsigned short* Vb = vb + (size_t)bh * ND * NL;

    bf16x8 qfr[2][2];
    #pragma unroll
    for (int mt = 0; mt < 2; mt++)
        #pragma unroll
        for (int kc = 0; kc < 2; kc++)
            qfr[mt][kc] = *(const bf16x8*)&Qb[(size_t)(qt * 128 + wave * 32 + mt * 16 + li) * ND +
                                             kc * 32 + quad * 8];

    const f32x4 fzero = {0.f, 0.f, 0.f, 0.f};
    float lsum[2] = {0.f, 0.f};
    f32x4 oacc[2][4];
    #pragma unroll
    for (int mt = 0; mt < 2; mt++)
        #pragma unroll
        for (int dt = 0; dt < 4; dt++) oacc[mt][dt] = fzero;

    const int kch = tid & 7, kjj = tid >> 3;
    const int vch = tid & 15, vdd = tid >> 4;

    uint4 kreg[4], vreg[4];
    #pragma unroll
    for (int rep = 0; rep < 4; rep++) {
        kreg[rep] = *(const uint4*)&Kb[(size_t)(kjj + rep * 32) * ND + kch * 8];
        vreg[rep] = *(const uint4*)&Vb[(size_t)(vdd + rep * 16) * NL + vch * 8];
    }

    for (int kt = 0; kt < 16; kt++) {
        #pragma unroll
        for (int rep = 0; rep < 4; rep++) {
            *(uint4*)&Kt[(kjj + rep * 32) * 72 + kch * 8] = kreg[rep];
            *(uint4*)&Vt[(vdd + rep * 16) * 136 + vch * 8] = vreg[rep];
        }
        __syncthreads();
        const int j0n = (kt + 1) * 128;
        // K prefetch: live through the S phase (16 VGPRs)
        if (kt < 15) {
            #pragma unroll
            for (int rep = 0; rep < 4; rep++)
                kreg[rep] = *(const uint4*)&Kb[(size_t)(j0n + kjj + rep * 32) * ND + kch * 8];
        }

        // S^T = K Q^T
        f32x4 st[2][8];
        #pragma unroll
        for (int mt = 0; mt < 2; mt++)
            #pragma unroll
            for (int jt = 0; jt < 8; jt++) st[mt][jt] = fzero;
        #pragma unroll
        for (int kc = 0; kc < 2; kc++)
            #pragma unroll
            for (int jt = 0; jt < 8; jt++) {
                bf16x8 kfr = *(const bf16x8*)&Kt[(jt * 16 + li) * 72 + kc * 32 + quad * 8];
                st[0][jt] = __builtin_amdgcn_mfma_f32_16x16x32_bf16(kfr, qfr[0][kc], st[0][jt], 0, 0, 0);
                st[1][jt] = __builtin_amdgcn_mfma_f32_16x16x32_bf16(kfr, qfr[1][kc], st[1][jt], 0, 0, 0);
            }

        // P = exp2(S), per-lane row-sum, bf16 pack (st dies into pk here)
        unsigned pk[2][8][2];
        #pragma unroll
        for (int mt = 0; mt < 2; mt++) {
            float ps = 0.f;
            #pragma unroll
            for (int jt = 0; jt < 8; jt++) {
                float p0 = fexp2(st[mt][jt][0]);
                float p1 = fexp2(st[mt][jt][1]);
                float p2 = fexp2(st[mt][jt][2]);
                float p3 = fexp2(st[mt][jt][3]);
                ps += (p0 + p1) + (p2 + p3);
                pk[mt][jt][0] = pack_bf16_ru(p0, p1);
                pk[mt][jt][1] = pack_bf16_ru(p2, p3);
            }
            lsum[mt] += ps;
        }

        // V prefetch: issued only now, in the low-pressure PV phase (16 VGPRs)
        if (kt < 15) {
            #pragma unroll
            for (int rep = 0; rep < 4; rep++)
                vreg[rep] = *(const uint4*)&Vb[(size_t)(vdd + rep * 16) * NL + j0n + vch * 8];
        }

        // register relayout C/D -> B-frags
        #pragma unroll
        for (int mt = 0; mt < 2; mt++)
            #pragma unroll
            for (int kc = 0; kc < 4; kc++)
                #pragma unroll
                for (int p = 0; p < 2; p++)
                    pfr_quad_swap(pk[mt][2 * kc][p], pk[mt][2 * kc + 1][p]);

        // O^T += V^T P^T
        #pragma unroll
        for (int kc = 0; kc < 4; kc++) {
            union { unsigned u[4]; bf16x8 v; } pf0, pf1;
            pf0.u[0] = pk[0][2 * kc][0]; pf0.u[1] = pk[0][2 * kc][1];
            pf0.u[2] = pk[0][2 * kc + 1][0]; pf0.u[3] = pk[0][2 * kc + 1][1];
            pf1.u[0] = pk[1][2 * kc][0]; pf1.u[1] = pk[1][2 * kc][1];
            pf1.u[2] = pk[1][2 * kc + 1][0]; pf1.u[3] = pk[1][2 * kc + 1][1];
            #pragma unroll
            for (int dt = 0; dt < 4; dt++) {
                bf16x8 vfr = *(const bf16x8*)&Vt[(dt * 16 + li) * 136 + kc * 32 + quad * 8];
                oacc[0][dt] = __builtin_amdgcn_mfma_f32_16x16x32_bf16(vfr, pf0.v, oacc[0][dt], 0, 0, 0);
                oacc[1][dt] = __builtin_amdgcn_mfma_f32_16x16x32_bf16(vfr, pf1.v, oacc[1][dt], 0, 0, 0);
            }
        }
        __syncthreads();
    }

    #pragma unroll
    for (int mt = 0; mt < 2; mt++) {
        float s = lsum[mt];
        s += __shfl_xor(s, 16, 64);
        s += __shfl_xor(s, 32, 64);
        lsum[mt] = s;
    }

    #pragma unroll
    for (int mt = 0; mt < 2; mt++) {
        const float rl = 1.0f / lsum[mt];
        const int l = qt * 128 + wave * 32 + mt * 16 + li;
        #pragma unroll
        for (int dt = 0; dt < 4; dt++) {
            uint2 ov;
            ov.x = (unsigned)f2bf(oacc[mt][dt][0] * rl) |
                   ((unsigned)f2bf(oacc[mt][dt][1] * rl) << 16);
            ov.y = (unsigned)f2bf(oacc[mt][dt][2] * rl) |
                   ((unsigned)f2bf(oacc[mt][dt][3] * rl) << 16);
            *(uint2*)&at[((size_t)(b * NL + l)) * NHID + h * ND + dt * 16 + quad * 4] = ov;
        }
    }
}

// ---------------------------------------------------------------------------
// Kernel 3: output projection with register-prefetch software pipeline.
// ---------------------------------------------------------------------------
__global__ __launch_bounds__(256) void out_proj_kernel(
    const unsigned short* __restrict__ at, const float* __restrict__ w,
    const float* __restrict__ bias, float* __restrict__ out)
{
    __shared__ __align__(16) unsigned short Wl[128 * 40];
    __shared__ __align__(16) unsigned short Al[128 * 40];
    const int tid = threadIdx.x;
    const int wave = tid >> 6, lane = tid & 63;
    const int quad = lane >> 4, li = lane & 15;
    const int o0 = blockIdx.x * 128, l0 = blockIdx.y * 128, b = blockIdx.z;

    const f32x4 fzero = {0.f, 0.f, 0.f, 0.f};
    f32x4 acc[2][8];
    #pragma unroll
    for (int mt = 0; mt < 2; mt++)
        #pragma unroll
        for (int nt = 0; nt < 8; nt++) acc[mt][nt] = fzero;

    const int wcg = tid & 7, woo = tid >> 3;
    const int ach = tid & 3, al0 = tid >> 2;

    float4 wv[4];
    uint4 av[2];
    #pragma unroll
    for (int rep = 0; rep < 4; rep++)
        wv[rep] = *(const float4*)&w[(size_t)(o0 + woo + rep * 32) * NHID + wcg * 4];
    #pragma unroll
    for (int rep = 0; rep < 2; rep++)
        av[rep] = *(const uint4*)&at[(size_t)(b * NL + l0 + al0 + rep * 64) * NHID + ach * 8];

    for (int c0 = 0; c0 < NHID; c0 += 32) {
        #pragma unroll
        for (int rep = 0; rep < 4; rep++) {
            uint2 val;
            val.x = (unsigned)f2bf(wv[rep].x) | ((unsigned)f2bf(wv[rep].y) << 16);
            val.y = (unsigned)f2bf(wv[rep].z) | ((unsigned)f2bf(wv[rep].w) << 16);
            *(uint2*)&Wl[(woo + rep * 32) * 40 + wcg * 4] = val;
        }
        #pragma unroll
        for (int rep = 0; rep < 2; rep++)
            *(uint4*)&Al[(al0 + rep * 64) * 40 + ach * 8] = av[rep];
        __syncthreads();
        if (c0 + 32 < NHID) {
            const int c1 = c0 + 32;
            #pragma unroll
            for (int rep = 0; rep < 4; rep++)
                wv[rep] = *(const float4*)&w[(size_t)(o0 + woo + rep * 32) * NHID + c1 + wcg * 4];
            #pragma unroll
            for (int rep = 0; rep < 2; rep++)
                av[rep] = *(const uint4*)&at[(size_t)(b * NL + l0 + al0 + rep * 64) * NHID + c1 + ach * 8];
        }
        bf16x8 afr0 = *(const bf16x8*)&Wl[(wave * 32 + li) * 40 + quad * 8];
        bf16x8 afr1 = *(const bf16x8*)&Wl[(wave * 32 + 16 + li) * 40 + quad * 8];
        #pragma unroll
        for (int nt = 0; nt < 8; nt++) {
            bf16x8 bfr = *(const bf16x8*)&Al[(nt * 16 + li) * 40 + quad * 8];
            acc[0][nt] = __builtin_amdgcn_mfma_f32_16x16x32_bf16(afr0, bfr, acc[0][nt], 0, 0, 0);
            acc[1][nt] = __builtin_amdgcn_mfma_f32_16x16x32_bf16(afr1, bfr, acc[1][nt], 0, 0, 0);
        }
        __syncthreads();
    }

    #pragma unroll
    for (int mt = 0; mt < 2; mt++) {
        int or0 = o0 + wave * 32 + mt * 16 + quad * 4;
        #pragma unroll
        for (int nt = 0; nt < 8; nt++) {
            int l = l0 + nt * 16 + li;
            #pragma unroll
            for (int r = 0; r < 4; r++)
                out[((size_t)(b * NC + or0 + r)) * NL + l] = acc[mt][nt][r] + bias[or0 + r];
        }
    }
}

extern "C" void kernel_launch(void* const* d_in, const int* in_sizes, int n_in,
                              void* d_out, int out_size, void* d_ws, size_t ws_size,
                              hipStream_t stream) {
    const float* x = (const float*)d_in[0];
    const float* w_qkv = (const float*)d_in[1];
    const float* w_out = (const float*)d_in[2];
    const float* b_out = (const float*)d_in[3];
    float* out = (float*)d_out;

    unsigned short* ws = (unsigned short*)d_ws;
    const size_t SZ = (size_t)NB * NH * NL * ND;
    unsigned short* qb = ws;
    unsigned short* kb = qb + SZ;
    unsigned short* vb = kb + SZ;
    unsigned short* at = vb + SZ;

    qkv_proj_kernel<<<dim3(12, 16, 8), dim3(256), 0, stream>>>(x, w_qkv, qb, kb, vb);
    attn_kernel<<<dim3(16, 8, 8), dim3(256), 0, stream>>>(qb, kb, vb, at);
    out_proj_kernel<<<dim3(4, 16, 8), dim3(256), 0, stream>>>(at, w_out, b_out, out);
}